// Round 1
// 9393.127 us; speedup vs baseline: 1.1879x; 1.1879x over previous
//
#include <hip/hip_runtime.h>
#include <stdint.h>

#define B_ 4
#define T_ 512
#define D_ 512
#define H_ 1024
#define V_ 50000
#define VPAD 50048
#define M_ (B_*T_)   // 2048 rows (b*T+t)
#define G4 (4*H_)    // 4096 gate rows

typedef __attribute__((ext_vector_type(8))) short bf16x8;
typedef __attribute__((ext_vector_type(4))) float f32x4;

__device__ __forceinline__ ushort f2bf(float f){
  uint32_t u = __float_as_uint(f);
  u += 0x7fffu + ((u >> 16) & 1u);
  return (ushort)(u >> 16);
}

// ---- fp32 -> bf16 conversion, zero-pads dst beyond src ----
__global__ void cvt4_kernel(const float* __restrict__ src, ushort* __restrict__ dst,
                            int n4_src, int n4_dst){
  int i = blockIdx.x * blockDim.x + threadIdx.x;
  if (i >= n4_dst) return;
  ushort4 r; r.x = 0; r.y = 0; r.z = 0; r.w = 0;
  if (i < n4_src){
    float4 v = reinterpret_cast<const float4*>(src)[i];
    r.x = f2bf(v.x); r.y = f2bf(v.y); r.z = f2bf(v.z); r.w = f2bf(v.w);
  }
  reinterpret_cast<ushort4*>(dst)[i] = r;
}

// ---- embedding gather -> bf16 [2048][512] ----
__global__ void gather_kernel(const int* __restrict__ idx, const float* __restrict__ X,
                              ushort* __restrict__ emb){
  int row = blockIdx.x;                 // b*T + t
  int tok = idx[row];
  const float* src = X + (size_t)tok * D_;
  ushort* dst = emb + (size_t)row * D_;
  for (int k = threadIdx.x; k < D_; k += blockDim.x) dst[k] = f2bf(src[k]);
}

// ---- C[M x ldc](f32) = A[Mx K]bf16 * B[Npad x K]bf16^T + bias ----
// tiles 128x128, BK=64, 256 thr = 4 waves (2x2 of 64x64), 16x16x32 bf16 MFMA
__global__ __launch_bounds__(256) void gemm_kernel(
    const ushort* __restrict__ A, const ushort* __restrict__ Bm,
    const float* __restrict__ bias, float* __restrict__ C,
    int K, int Nreal, int ldc){
  __shared__ ushort As[128*64];
  __shared__ ushort Bs[128*64];
  const int tid = threadIdx.x;
  const int w = tid >> 6, l = tid & 63;
  const int tm = blockIdx.y, tn = blockIdx.x;
  const int wm = (w >> 1) * 64, wn = (w & 1) * 64;
  const int lq = l & 15, quad = l >> 4;

  f32x4 acc[4][4];
  #pragma unroll
  for (int i = 0; i < 4; i++)
    #pragma unroll
    for (int j = 0; j < 4; j++) acc[i][j] = (f32x4){0.f,0.f,0.f,0.f};

  const int srow = l >> 3;              // row within 8-row group
  const int sg   = (l & 7) ^ srow;      // swizzled source granule

  for (int kt = 0; kt < K; kt += 64){
    #pragma unroll
    for (int q = 0; q < 4; q++){
      const int iss = w*4 + q;          // 0..15, each covers 8 rows
      const int row = iss*8 + srow;
      const ushort* ga = A  + (size_t)(tm*128 + row)*K + kt + sg*8;
      const ushort* gb = Bm + (size_t)(tn*128 + row)*K + kt + sg*8;
      __builtin_amdgcn_global_load_lds((const __attribute__((address_space(1))) void*)ga,
          (__attribute__((address_space(3))) void*)(&As[iss*512]), 16, 0, 0);
      __builtin_amdgcn_global_load_lds((const __attribute__((address_space(1))) void*)gb,
          (__attribute__((address_space(3))) void*)(&Bs[iss*512]), 16, 0, 0);
    }
    __syncthreads();
    #pragma unroll
    for (int kc = 0; kc < 2; kc++){
      bf16x8 af[4], bfv[4];
      const int G = kc*4 + quad;
      #pragma unroll
      for (int i = 0; i < 4; i++){
        int rowA = wm + i*16 + lq;
        af[i] = *reinterpret_cast<const bf16x8*>(&As[rowA*64 + (G ^ (rowA & 7))*8]);
        int rowB = wn + i*16 + lq;
        bfv[i] = *reinterpret_cast<const bf16x8*>(&Bs[rowB*64 + (G ^ (rowB & 7))*8]);
      }
      #pragma unroll
      for (int i = 0; i < 4; i++)
        #pragma unroll
        for (int j = 0; j < 4; j++)
          acc[i][j] = __builtin_amdgcn_mfma_f32_16x16x32_bf16(af[i], bfv[j], acc[i][j], 0, 0, 0);
    }
    __syncthreads();
  }
  #pragma unroll
  for (int j = 0; j < 4; j++){
    int col = tn*128 + wn + j*16 + lq;
    bool ok = col < Nreal;
    float bv = ok ? bias[col] : 0.f;
    #pragma unroll
    for (int i = 0; i < 4; i++){
      int row0 = tm*128 + wm + i*16 + quad*4;
      #pragma unroll
      for (int r = 0; r < 4; r++){
        if (ok) C[(size_t)(row0 + r)*ldc + col] = acc[i][j][r] + bv;
      }
    }
  }
}

// ---- persistent LSTM layer: all 512 timesteps in ONE launch ----
// 64 WGs x 256 thr; WG wg owns h columns [wg*16, wg*16+16); wave w = gate w.
// Whh fragments preloaded into 128 VGPRs/thread and reused across all steps.
// Cross-WG dependency (full h each step) via monotonic-counter grid barrier.
// All 64 WGs trivially co-resident (<= 256 CUs, ~1KB LDS, ~220 VGPR).
__global__ __launch_bounds__(256, 1) void lstm_persist_kernel(
    const ushort* __restrict__ Whh,   // [4096][1024] bf16
    const float*  __restrict__ xg,    // [2048][4096] f32 (row = b*T+t), bias pre-added
    ushort* __restrict__ hbuf,        // [2][4][1024] bf16 ping-pong (pre-zeroed)
    ushort* __restrict__ hseq,        // [2048][1024] bf16
    unsigned int* __restrict__ barcnt){ // pre-zeroed
  const int tid = threadIdx.x;
  const int w = tid >> 6, l = tid & 63;
  const int wg = blockIdx.x;          // 0..63
  const int lq = l & 15, quad = l >> 4;
  __shared__ float gates[4][4][16];   // [gate][batch][j]

  // ---- one-time: Whh slice -> registers (32 x bf16x8 = 128 VGPR) ----
  const ushort* wp = Whh + (size_t)(w*H_ + wg*16 + lq)*H_ + quad*8;
  bf16x8 bfr[32];
  #pragma unroll
  for (int c = 0; c < 32; c++) bfr[c] = *reinterpret_cast<const bf16x8*>(wp + c*32);

  // gate-math thread mapping (tid<64): b = tid>>4, j = tid&15
  const int gb = tid >> 4, gj = tid & 15;
  const int jj = wg*16 + gj;
  const bool gm = (tid < 64);
  float creg = 0.f;                   // cell state lives in a register

  // prefetch xg for t=0
  float xv0 = 0.f, xv1 = 0.f, xv2 = 0.f, xv3 = 0.f;
  if (gm){
    const size_t xb = ((size_t)gb*T_ + 0)*G4 + jj;
    xv0 = xg[xb];        xv1 = xg[xb + H_];
    xv2 = xg[xb + 2*H_]; xv3 = xg[xb + 3*H_];
  }
  const unsigned int nwg = gridDim.x;

  for (int t = 0; t < T_; t++){
    const ushort* hin  = hbuf + (size_t)(t & 1)*(B_*H_);
    ushort*       hout = hbuf + (size_t)((t + 1) & 1)*(B_*H_);
    const ushort* ap = hin + (size_t)(lq & 3)*H_ + quad*8;  // batches dup'd to rows 4..15

    f32x4 acc0 = (f32x4){0.f,0.f,0.f,0.f};
    f32x4 acc1 = (f32x4){0.f,0.f,0.f,0.f};
    #pragma unroll
    for (int cc = 0; cc < 4; cc++){
      bf16x8 a[8];
      #pragma unroll
      for (int c = 0; c < 8; c++) a[c] = *reinterpret_cast<const bf16x8*>(ap + (cc*8 + c)*32);
      #pragma unroll
      for (int c = 0; c < 4; c++){
        acc0 = __builtin_amdgcn_mfma_f32_16x16x32_bf16(a[2*c],   bfr[cc*8 + 2*c],   acc0, 0, 0, 0);
        acc1 = __builtin_amdgcn_mfma_f32_16x16x32_bf16(a[2*c+1], bfr[cc*8 + 2*c+1], acc1, 0, 0, 0);
      }
    }
    if (l < 16){                      // quad 0 holds D rows 0..3 = batches
      #pragma unroll
      for (int r = 0; r < 4; r++) gates[w][r][l] = acc0[r] + acc1[r];
    }
    __syncthreads();
    if (gm){
      float pi = gates[0][gb][gj] + xv0;
      float pf = gates[1][gb][gj] + xv1;
      float pg = gates[2][gb][gj] + xv2;
      float po = gates[3][gb][gj] + xv3;
      float ig = 1.f/(1.f + __expf(-pi));
      float fg = 1.f/(1.f + __expf(-pf));
      float gv = tanhf(pg);
      float og = 1.f/(1.f + __expf(-po));
      creg = fg * creg + ig * gv;
      float h  = og * tanhf(creg);
      ushort hb = f2bf(h);
      hout[gb*H_ + jj] = hb;
      hseq[((size_t)gb*T_ + t)*H_ + jj] = hb;
      if (t + 1 < T_){                // prefetch next step's xg (h-independent)
        const size_t xb = ((size_t)gb*T_ + (t + 1))*G4 + jj;
        xv0 = xg[xb];        xv1 = xg[xb + H_];
        xv2 = xg[xb + 2*H_]; xv3 = xg[xb + 3*H_];
      }
    }
    // ---- grid barrier: release h stores, arrive, spin, acquire ----
    __syncthreads();                  // drains vmcnt: WG's h stores are in L2
    if (tid == 0){
      __threadfence();                // agent release (L2 writeback for cross-XCD)
      __hip_atomic_fetch_add(barcnt, 1u, __ATOMIC_RELAXED, __HIP_MEMORY_SCOPE_AGENT);
      const unsigned int tgt = (unsigned int)(t + 1) * nwg;
      while (__hip_atomic_load(barcnt, __ATOMIC_RELAXED, __HIP_MEMORY_SCOPE_AGENT) < tgt)
        __builtin_amdgcn_s_sleep(1);
      __threadfence();                // agent acquire (L1/L2 invalidate)
    }
    __syncthreads();
  }
}

// ---- log-softmax: logits are tiny (|x|<~2), so direct log(sum exp(x)) is safe ----
__global__ void lse_kernel(const float* __restrict__ out, float* __restrict__ rowlse){
  int row = blockIdx.x;
  const float* p = out + (size_t)row * V_;
  float s = 0.f;
  for (int k = threadIdx.x; k < V_; k += blockDim.x) s += __expf(p[k]);
  #pragma unroll
  for (int off = 32; off > 0; off >>= 1) s += __shfl_down(s, off);
  __shared__ float red[4];
  if ((threadIdx.x & 63) == 0) red[threadIdx.x >> 6] = s;
  __syncthreads();
  if (threadIdx.x == 0) rowlse[row] = logf(red[0] + red[1] + red[2] + red[3]);
}

__global__ void apply_kernel(float* __restrict__ out, const float* __restrict__ rowlse){
  int row = blockIdx.y;
  int xi = blockIdx.x * blockDim.x + threadIdx.x;
  if (xi >= V_/4) return;
  float4* p = reinterpret_cast<float4*>(out + (size_t)row * V_);
  float ls = rowlse[row];
  float4 v = p[xi];
  v.x -= ls; v.y -= ls; v.z -= ls; v.w -= ls;
  p[xi] = v;
}

extern "C" void kernel_launch(void* const* d_in, const int* in_sizes, int n_in,
                              void* d_out, int out_size, void* d_ws, size_t ws_size,
                              hipStream_t stream){
  const int*   idx   = (const int*)  d_in[0];
  const float* X     = (const float*)d_in[1];
  const float* Wih0  = (const float*)d_in[2];
  const float* Whh0  = (const float*)d_in[3];
  const float* b0    = (const float*)d_in[4];
  const float* Wih1  = (const float*)d_in[5];
  const float* Whh1  = (const float*)d_in[6];
  const float* b1    = (const float*)d_in[7];
  const float* Wout  = (const float*)d_in[8];
  const float* bout  = (const float*)d_in[9];
  float* out = (float*)d_out;

  char* ws = (char*)d_ws;
  size_t off = 0;
  auto alloc = [&](size_t bytes){ void* p = ws + off; off = (off + bytes + 255) & ~(size_t)255; return p; };
  ushort* emb   = (ushort*)alloc((size_t)M_*D_*2);      //   2.0 MB
  ushort* wih0b = (ushort*)alloc((size_t)G4*D_*2);      //   4.2 MB
  ushort* whh0b = (ushort*)alloc((size_t)G4*H_*2);      //   8.4 MB
  ushort* wih1b = (ushort*)alloc((size_t)G4*H_*2);      //   8.4 MB
  ushort* whh1b = (ushort*)alloc((size_t)G4*H_*2);      //   8.4 MB
  ushort* woutb = (ushort*)alloc((size_t)VPAD*H_*2);    // 102.5 MB (padded w/ zero rows)
  float*  xgbuf = (float*)alloc((size_t)M_*G4*4);       //  33.6 MB (shared by layer 0 & 1)
  ushort* h0seq = (ushort*)alloc((size_t)M_*H_*2);      //   4.2 MB
  ushort* h1seq = (ushort*)alloc((size_t)M_*H_*2);      //   4.2 MB
  ushort* hb0   = (ushort*)alloc(2*(size_t)B_*H_*2);    // ping-pong h state L0
  ushort* hb1   = (ushort*)alloc(2*(size_t)B_*H_*2);
  float*  rowlse= (float*) alloc((size_t)M_*4);
  unsigned int* bar = (unsigned int*)alloc(256);        // two barrier counters

  // weight conversions to bf16 (W_out zero-padded to 50048 rows)
  {
    int n4;
    n4 = G4*D_/4; cvt4_kernel<<<(n4+255)/256, 256, 0, stream>>>(Wih0, wih0b, n4, n4);
    n4 = G4*H_/4; cvt4_kernel<<<(n4+255)/256, 256, 0, stream>>>(Whh0, whh0b, n4, n4);
    n4 = G4*H_/4; cvt4_kernel<<<(n4+255)/256, 256, 0, stream>>>(Wih1, wih1b, n4, n4);
    n4 = G4*H_/4; cvt4_kernel<<<(n4+255)/256, 256, 0, stream>>>(Whh1, whh1b, n4, n4);
    int n4d = VPAD*H_/4, n4s = V_*H_/4;
    cvt4_kernel<<<(n4d+255)/256, 256, 0, stream>>>(Wout, woutb, n4s, n4d);
  }
  gather_kernel<<<M_, 256, 0, stream>>>(idx, X, emb);

  // zero recurrent state + barrier counters (ws is poisoned 0xAA every call)
  hipMemsetAsync(hb0, 0, 2*(size_t)B_*H_*2, stream);
  hipMemsetAsync(hb1, 0, 2*(size_t)B_*H_*2, stream);
  hipMemsetAsync(bar, 0, 256, stream);

  // layer 0: xg0 = emb @ Wih0^T + b0 ; then ONE persistent kernel for 512 steps
  gemm_kernel<<<dim3(G4/128, M_/128), 256, 0, stream>>>(emb, wih0b, b0, xgbuf, D_, G4, G4);
  lstm_persist_kernel<<<64, 256, 0, stream>>>(whh0b, xgbuf, hb0, h0seq, bar + 0);

  // layer 1
  gemm_kernel<<<dim3(G4/128, M_/128), 256, 0, stream>>>(h0seq, wih1b, b1, xgbuf, H_, G4, G4);
  lstm_persist_kernel<<<64, 256, 0, stream>>>(whh1b, xgbuf, hb1, h1seq, bar + 64);

  // logits = h1seq @ Wout^T + b_out  -> d_out, then in-place log_softmax
  gemm_kernel<<<dim3(VPAD/128, M_/128), 256, 0, stream>>>(h1seq, woutb, bout, out, H_, V_, V_);
  lse_kernel<<<M_, 256, 0, stream>>>(out, rowlse);
  apply_kernel<<<dim3((V_/4+255)/256, M_), 256, 0, stream>>>(out, rowlse);
}